// Round 1
// baseline (67.701 us; speedup 1.0000x reference)
//
#include <hip/hip_runtime.h>
#include <float.h>

#define N_NODES 200000
#define D 256
#define HID 512
#define OUTD 2
#define NG 512

// ---------------------------------------------------------------------------
// Kernel 1: segment boundaries from sorted batch vector.
// row_start[g] = first node index i with batch[i] >= g;  row_start[NG] = N.
// ---------------------------------------------------------------------------
__global__ void k_bounds(const int* __restrict__ batch, int* __restrict__ row_start, int n) {
    int i = blockIdx.x * blockDim.x + threadIdx.x;
    if (i >= n) return;
    int b  = batch[i];
    int bp = (i == 0) ? -1 : batch[i - 1];
    for (int g = bp + 1; g <= b; ++g) row_start[g] = i;
    if (i == n - 1) {
        for (int g = b + 1; g <= NG; ++g) row_start[g] = n;
    }
}

// ---------------------------------------------------------------------------
// Kernel 2: segment max pooling. One block (4 waves) per graph.
// Lane l of each wave owns float4 at cols [4l, 4l+4); waves stride rows by 4.
// ---------------------------------------------------------------------------
__global__ __launch_bounds__(256) void k_pool(const float* __restrict__ x,
                                              const int* __restrict__ row_start,
                                              float* __restrict__ gp) {
    const int g    = blockIdx.x;
    const int lane = threadIdx.x & 63;
    const int wave = threadIdx.x >> 6;
    const int r0 = row_start[g];
    const int r1 = row_start[g + 1];

    float4 m = make_float4(-FLT_MAX, -FLT_MAX, -FLT_MAX, -FLT_MAX);
    const float* xc = x + (size_t)lane * 4;

    int r = r0 + wave;
    // 4x unrolled: 4 independent 16B loads in flight per lane
    for (; r + 12 < r1; r += 16) {
        float4 v0 = *reinterpret_cast<const float4*>(xc + (size_t)r * D);
        float4 v1 = *reinterpret_cast<const float4*>(xc + (size_t)(r + 4) * D);
        float4 v2 = *reinterpret_cast<const float4*>(xc + (size_t)(r + 8) * D);
        float4 v3 = *reinterpret_cast<const float4*>(xc + (size_t)(r + 12) * D);
        m.x = fmaxf(m.x, fmaxf(fmaxf(v0.x, v1.x), fmaxf(v2.x, v3.x)));
        m.y = fmaxf(m.y, fmaxf(fmaxf(v0.y, v1.y), fmaxf(v2.y, v3.y)));
        m.z = fmaxf(m.z, fmaxf(fmaxf(v0.z, v1.z), fmaxf(v2.z, v3.z)));
        m.w = fmaxf(m.w, fmaxf(fmaxf(v0.w, v1.w), fmaxf(v2.w, v3.w)));
    }
    for (; r < r1; r += 4) {
        float4 v = *reinterpret_cast<const float4*>(xc + (size_t)r * D);
        m.x = fmaxf(m.x, v.x); m.y = fmaxf(m.y, v.y);
        m.z = fmaxf(m.z, v.z); m.w = fmaxf(m.w, v.w);
    }

    __shared__ float4 lds[4][64];
    lds[wave][lane] = m;
    __syncthreads();
    if (wave == 0) {
        float4 a = lds[0][lane], b = lds[1][lane], c = lds[2][lane], d = lds[3][lane];
        float4 o;
        o.x = fmaxf(fmaxf(a.x, b.x), fmaxf(c.x, d.x));
        o.y = fmaxf(fmaxf(a.y, b.y), fmaxf(c.y, d.y));
        o.z = fmaxf(fmaxf(a.z, b.z), fmaxf(c.z, d.z));
        o.w = fmaxf(fmaxf(a.w, b.w), fmaxf(c.w, d.w));
        if (r1 == r0) o = make_float4(0.f, 0.f, 0.f, 0.f);  // empty graph -> zeros
        *reinterpret_cast<float4*>(gp + (size_t)g * D + lane * 4) = o;
    }
}

// ---------------------------------------------------------------------------
// Kernel 3: 32x32-tile f32 GEMM, C = act(A[M,K] @ B[K,N] + bias), row-major.
// 256 threads, each computes a 2x2 micro-tile. M,N multiples of 32; K mult 32.
// ---------------------------------------------------------------------------
template <int K, bool RELU>
__global__ __launch_bounds__(256) void k_gemm(const float* __restrict__ A,
                                              const float* __restrict__ B,
                                              const float* __restrict__ bias,
                                              float* __restrict__ C, int N) {
    __shared__ float As[32][33];
    __shared__ float Bs[32][33];
    const int t  = threadIdx.x;
    const int bm = blockIdx.y * 32;
    const int bn = blockIdx.x * 32;
    const int lr = t >> 3;            // 0..31
    const int lc = (t & 7) << 2;      // 0,4,...,28
    const int tx = t & 15;            // col group
    const int ty = t >> 4;            // row group
    float acc00 = 0.f, acc01 = 0.f, acc10 = 0.f, acc11 = 0.f;

    for (int k0 = 0; k0 < K; k0 += 32) {
        float4 av = *reinterpret_cast<const float4*>(A + (size_t)(bm + lr) * K + k0 + lc);
        float4 bv = *reinterpret_cast<const float4*>(B + (size_t)(k0 + lr) * N + bn + lc);
        __syncthreads();
        As[lr][lc] = av.x; As[lr][lc + 1] = av.y; As[lr][lc + 2] = av.z; As[lr][lc + 3] = av.w;
        Bs[lr][lc] = bv.x; Bs[lr][lc + 1] = bv.y; Bs[lr][lc + 2] = bv.z; Bs[lr][lc + 3] = bv.w;
        __syncthreads();
#pragma unroll
        for (int kk = 0; kk < 32; ++kk) {
            float a0 = As[ty * 2][kk], a1 = As[ty * 2 + 1][kk];
            float b0 = Bs[kk][tx * 2], b1 = Bs[kk][tx * 2 + 1];
            acc00 += a0 * b0; acc01 += a0 * b1;
            acc10 += a1 * b0; acc11 += a1 * b1;
        }
    }

    const int r = bm + ty * 2, c = bn + tx * 2;
    float bc0 = bias[c], bc1 = bias[c + 1];
    float v00 = acc00 + bc0, v01 = acc01 + bc1;
    float v10 = acc10 + bc0, v11 = acc11 + bc1;
    if (RELU) {
        v00 = fmaxf(v00, 0.f); v01 = fmaxf(v01, 0.f);
        v10 = fmaxf(v10, 0.f); v11 = fmaxf(v11, 0.f);
    }
    C[(size_t)r * N + c]           = v00;
    C[(size_t)r * N + c + 1]       = v01;
    C[(size_t)(r + 1) * N + c]     = v10;
    C[(size_t)(r + 1) * N + c + 1] = v11;
}

// ---------------------------------------------------------------------------
// Kernel 4: final [512,HID] @ [HID,2] + b3. One wave per output element.
// ---------------------------------------------------------------------------
__global__ __launch_bounds__(256) void k_fc3(const float* __restrict__ h,
                                             const float* __restrict__ W,
                                             const float* __restrict__ b,
                                             float* __restrict__ out) {
    const int wave = threadIdx.x >> 6;
    const int lane = threadIdx.x & 63;
    const int e = blockIdx.x * 4 + wave;        // 0..NG*OUTD-1
    const int row = e >> 1, col = e & 1;
    float s = 0.f;
#pragma unroll
    for (int k = lane; k < HID; k += 64)
        s += h[(size_t)row * HID + k] * W[(size_t)k * OUTD + col];
#pragma unroll
    for (int off = 32; off; off >>= 1) s += __shfl_xor(s, off);
    if (lane == 0) out[e] = s + b[col];
}

// ---------------------------------------------------------------------------
extern "C" void kernel_launch(void* const* d_in, const int* in_sizes, int n_in,
                              void* d_out, int out_size, void* d_ws, size_t ws_size,
                              hipStream_t stream) {
    const float* x     = (const float*)d_in[0];
    const int*   batch = (const int*)d_in[1];
    const float* W1    = (const float*)d_in[2];
    const float* b1    = (const float*)d_in[3];
    const float* W2    = (const float*)d_in[4];
    const float* b2    = (const float*)d_in[5];
    const float* W3    = (const float*)d_in[6];
    const float* b3    = (const float*)d_in[7];
    float* out = (float*)d_out;

    char* ws = (char*)d_ws;
    int*   row_start = (int*)ws;                                   // 513 ints
    float* gp = (float*)(ws + 4096);                               // 512*256 f32 = 512KB
    float* h1 = (float*)(ws + 4096 + 512 * 1024);                  // 512*512 f32 = 1MB
    float* h2 = (float*)(ws + 4096 + 512 * 1024 + 1024 * 1024);    // 512*512 f32 = 1MB

    k_bounds<<<(N_NODES + 255) / 256, 256, 0, stream>>>(batch, row_start, N_NODES);
    k_pool<<<NG, 256, 0, stream>>>(x, row_start, gp);
    k_gemm<D,   true ><<<dim3(HID / 32, NG / 32), 256, 0, stream>>>(gp, W1, b1, h1, HID);
    k_gemm<HID, true ><<<dim3(HID / 32, NG / 32), 256, 0, stream>>>(h1, W2, b2, h2, HID);
    k_fc3<<<NG * OUTD / 4, 256, 0, stream>>>(h2, W3, b3, out);
}